// Round 1
// baseline (353.909 us; speedup 1.0000x reference)
//
#include <hip/hip_runtime.h>
#include <math.h>

#define NS 4096
#define NF 512
#define NB 16
#define NC 10
#define HSIZE 8192
#define HMASK 8191
#define HEMPTY 0xFFFFFFFFu

// ---------------- kernel 1: per-(b,c) class counts -> ws ----------------
__global__ void count_classes_kernel(const int* __restrict__ y, float* __restrict__ counts) {
    __shared__ int hist[NC];
    const int b = blockIdx.x;
    if (threadIdx.x < NC) hist[threadIdx.x] = 0;
    __syncthreads();
    for (int s = threadIdx.x; s < NS; s += blockDim.x)
        atomicAdd(&hist[y[b * NS + s]], 1);
    __syncthreads();
    if (threadIdx.x < NC) counts[b * NC + threadIdx.x] = (float)hist[threadIdx.x];
}

// ---------------- helpers ----------------
__device__ __forceinline__ float wave_reduce_add(float v) {
    #pragma unroll
    for (int off = 32; off > 0; off >>= 1) v += __shfl_down(v, off, 64);
    return v;
}
__device__ __forceinline__ float wave_reduce_max(float v) {
    #pragma unroll
    for (int off = 32; off > 0; off >>= 1) v = fmaxf(v, __shfl_down(v, off, 64));
    return v;
}

// ---------------- kernel 2: fused stats + hash-unique + MLP ----------------
// one 256-thread workgroup per (b, f) column
__launch_bounds__(256)
__global__ void fused_stats_mlp_kernel(const float* __restrict__ X,
                                       const int* __restrict__ y,
                                       const float* __restrict__ counts,
                                       const float* __restrict__ w1,
                                       const float* __restrict__ b1,
                                       const float* __restrict__ w2,
                                       const float* __restrict__ b2,
                                       float* __restrict__ out) {
    __shared__ unsigned int hash[HSIZE];   // 32 KB open-addressing set
    __shared__ float red[4][16];
    __shared__ float stats_s[6];
    __shared__ float h_s[64];

    // XCD-aware swizzle: consecutive columns (sharing cache lines) land on one XCD
    const int w = blockIdx.x;
    const int g = (w & 7) * 1024 + (w >> 3);   // bijection over [0, 8192)
    const int b = g >> 9;
    const int f = g & (NF - 1);
    const int tid = threadIdx.x;

    #pragma unroll
    for (int i = 0; i < HSIZE / 256; i++) hash[tid + i * 256] = HEMPTY;
    __syncthreads();

    const float* Xp = X + (size_t)b * NS * NF + f;
    const int*   yp = y + b * NS;

    float sum = 0.f, sumsq = 0.f, sumabs = 0.f, maxabs = 0.f, nancnt = 0.f, uniq = 0.f;
    float csum[NC];
    #pragma unroll
    for (int c = 0; c < NC; c++) csum[c] = 0.f;

    #pragma unroll
    for (int k0 = 0; k0 < 16; k0 += 8) {
        float xv[8]; int yv[8];
        #pragma unroll
        for (int k = 0; k < 8; k++) {          // batch loads for MLP-in-flight
            const int s = (k0 + k) * 256 + tid;
            xv[k] = Xp[(size_t)s * NF];
            yv[k] = yp[s];
        }
        #pragma unroll
        for (int k = 0; k < 8; k++) {
            float x = xv[k];
            if (x != x) { nancnt += 1.f; x = 0.f; }   // nan_to_num
            sum += x;
            sumsq = fmaf(x, x, sumsq);
            const float a = fabsf(x);
            sumabs += a;
            maxabs = fmaxf(maxabs, a);
            const int yc = yv[k];
            #pragma unroll
            for (int c = 0; c < NC; c++) csum[c] += (yc == c) ? x : 0.f;
            // distinct-value insert (value-equality semantics: -0.0 == +0.0)
            unsigned int pat = __float_as_uint(x);
            if (pat == 0x80000000u) pat = 0u;
            unsigned int slot = (pat * 2654435761u) >> 19;   // top 13 bits -> [0,8192)
            for (;;) {
                const unsigned int old = atomicCAS(&hash[slot], HEMPTY, pat);
                if (old == HEMPTY) { uniq += 1.f; break; }   // first insertion of this value
                if (old == pat) break;                        // duplicate
                slot = (slot + 1) & HMASK;                    // linear probe
            }
        }
    }

    sum    = wave_reduce_add(sum);
    sumsq  = wave_reduce_add(sumsq);
    sumabs = wave_reduce_add(sumabs);
    nancnt = wave_reduce_add(nancnt);
    uniq   = wave_reduce_add(uniq);
    maxabs = wave_reduce_max(maxabs);
    #pragma unroll
    for (int c = 0; c < NC; c++) csum[c] = wave_reduce_add(csum[c]);

    const int wave = tid >> 6, lane = tid & 63;
    if (lane == 0) {
        red[wave][0] = sum;    red[wave][1] = sumsq; red[wave][2] = sumabs;
        red[wave][3] = nancnt; red[wave][4] = uniq;  red[wave][5] = maxabs;
        #pragma unroll
        for (int c = 0; c < NC; c++) red[wave][6 + c] = csum[c];
    }
    __syncthreads();

    if (tid == 0) {
        float t[16];
        #pragma unroll
        for (int v = 0; v < 16; v++) t[v] = red[0][v];
        #pragma unroll
        for (int wv = 1; wv < 4; wv++) {
            #pragma unroll
            for (int v = 0; v < 16; v++) {
                if (v == 5) t[v] = fmaxf(t[v], red[wv][v]);
                else        t[v] += red[wv][v];
            }
        }
        const float invS = 1.f / (float)NS;
        const float gmean    = t[0] * invS;
        const float variance = fmaxf(t[1] * invS - gmean * gmean, 0.f);  // biased var
        const float mean_abs = t[2] * invS;
        const float missing  = t[3] * invS;
        const float n_unique = t[4];
        const float max_abs  = t[5];
        float between = 0.f;
        #pragma unroll
        for (int c = 0; c < NC; c++) {
            const float cnt = counts[b * NC + c];
            const float cm  = t[6 + c] / fmaxf(cnt, 1.f);
            const float d   = cm - gmean;
            between += cnt * d * d;
        }
        between *= invS;                                   // counts.sum() == NS
        const float target = between / fmaxf(variance, 1e-6f);
        float st[6] = { target, missing, n_unique * invS, variance, mean_abs, max_abs };
        #pragma unroll
        for (int i = 0; i < 6; i++) {
            float v = st[i];
            if (!(fabsf(v) < INFINITY)) v = 0.f;           // nan_to_num(nan/±inf -> 0)
            stats_s[i] = v;
        }
    }
    __syncthreads();

    // MLP epilogue: 6 -> 64 (exact GELU) -> 128
    if (tid < 64) {
        float z = b1[tid];
        #pragma unroll
        for (int i = 0; i < 6; i++) z = fmaf(stats_s[i], w1[i * 64 + tid], z);
        h_s[tid] = 0.5f * z * (1.f + erff(z * 0.70710678118654752440f));
    }
    __syncthreads();
    if (tid < 128) {
        float o = b2[tid];
        #pragma unroll
        for (int j = 0; j < 64; j++) o = fmaf(h_s[j], w2[j * 128 + tid], o);
        out[(size_t)g * 128 + tid] = o;
    }
}

extern "C" void kernel_launch(void* const* d_in, const int* in_sizes, int n_in,
                              void* d_out, int out_size, void* d_ws, size_t ws_size,
                              hipStream_t stream) {
    const float* X  = (const float*)d_in[0];
    const int*   y  = (const int*)d_in[1];
    const float* w1 = (const float*)d_in[2];
    const float* b1 = (const float*)d_in[3];
    const float* w2 = (const float*)d_in[4];
    const float* b2 = (const float*)d_in[5];
    float* out    = (float*)d_out;
    float* counts = (float*)d_ws;          // 16*10 floats

    count_classes_kernel<<<NB, 256, 0, stream>>>(y, counts);
    fused_stats_mlp_kernel<<<NB * NF, 256, 0, stream>>>(X, y, counts, w1, b1, w2, b2, out);
}